// Round 2
// baseline (679.495 us; speedup 1.0000x reference)
//
#include <hip/hip_runtime.h>
#include <cstdint>
#include <cstddef>

// Problem constants
#define M_DIM 8192
#define N_DIM 4096
#define K_DIM 4096

#define BM 128
#define BN 128
#define BK 64   // int8 elements per K-step (64 bytes per LDS row)

using i32x4 = __attribute__((ext_vector_type(4))) int;

// Pack the low bytes of 4 int32 (each in [-128,127]) into one dword.
// 3x v_perm_b32: sel 0..3 picks bytes of arg1 (lo), 4..7 picks bytes of arg0 (hi).
__device__ __forceinline__ int pack4(i32x4 v) {
    unsigned t01 = __builtin_amdgcn_perm((unsigned)v.y, (unsigned)v.x, 0x00000400u); // [x.b0, y.b0, -, -]
    unsigned t23 = __builtin_amdgcn_perm((unsigned)v.w, (unsigned)v.z, 0x00000400u); // [z.b0, w.b0, -, -]
    return (int)__builtin_amdgcn_perm(t23, t01, 0x05040100u);                        // [x,y,z,w] low bytes
}

// Fully fused: reads int32 inputs directly (no pack kernels, no workspace),
// converts to int8 in registers during LDS staging, MFMA i8 GEMM, requant epilogue.
// C[m][n] = clamp(round((sum_k A[m][k]*B[n][k] + bias[n]) * (0.05*wscale[n]/0.1)))
__global__ __launch_bounds__(256) void qgemm_fused_kernel(const int* __restrict__ A32,
                                                          const int* __restrict__ B32,
                                                          const int* __restrict__ bias,
                                                          const float* __restrict__ wscale,
                                                          int* __restrict__ C) {
    __shared__ int8_t As[BM * BK];   // 8 KiB packed, row-major 128 x 64B
    __shared__ int8_t Bs[BN * BK];   // 8 KiB

    const int tid  = threadIdx.x;
    const int wave = tid >> 6;
    const int lane = tid & 63;
    const int bm = blockIdx.y;
    const int bn = blockIdx.x;

    const int wm = wave >> 1;   // 0..1 : row half of tile
    const int wn = wave & 1;    // 0..1 : col half of tile

    // Staging geometry: per load instruction a wave covers 4 rows x 256B int32
    // (16 lanes x 16B contiguous per row -> 16 cache lines, optimal).
    // Each lane packs its 4 int32 -> 4 bytes -> ds_write_b32 (2-way bank alias, free).
    const int srow = wave * 4 + (lane >> 4);   // 0..15: row within each 16-row group
    const int sch  = lane & 15;                // 16B int32 chunk within row

    const int* Ag = A32 + (size_t)(bm * BM + srow) * K_DIM + sch * 4;
    const int* Bg = B32 + (size_t)(bn * BN + srow) * K_DIM + sch * 4;

    int* AsW = (int*)&As[srow * BK + sch * 4];   // advance by 256 ints per 16 rows
    int* BsW = (int*)&Bs[srow * BK + sch * 4];

    // fragment geometry (unchanged from verified kernel)
    const int kq   = (lane >> 4) * 16;       // byte offset in 64B row
    const int mrow = wm * 64 + (lane & 15);
    const int nrow = wn * 64 + (lane & 15);

    i32x4 acc[4][4] = {};

    for (int kt = 0; kt < K_DIM; kt += BK) {
        // ---- stage: load int32, pack to int8 in regs, write LDS ----
        i32x4 a0[4], b0[4], a1[4], b1[4];
#pragma unroll
        for (int it = 0; it < 4; ++it) {
            a0[it] = *(const i32x4*)(Ag + (size_t)(it * 16) * K_DIM + kt);
            b0[it] = *(const i32x4*)(Bg + (size_t)(it * 16) * K_DIM + kt);
        }
        __syncthreads();   // all waves done reading LDS for previous tile
#pragma unroll
        for (int it = 0; it < 4; ++it) {
            a1[it] = *(const i32x4*)(Ag + (size_t)((it + 4) * 16) * K_DIM + kt);
            b1[it] = *(const i32x4*)(Bg + (size_t)((it + 4) * 16) * K_DIM + kt);
        }
#pragma unroll
        for (int it = 0; it < 4; ++it) {
            AsW[it * (16 * BK / 4)] = pack4(a0[it]);
            BsW[it * (16 * BK / 4)] = pack4(b0[it]);
        }
#pragma unroll
        for (int it = 0; it < 4; ++it) {
            AsW[(it + 4) * (16 * BK / 4)] = pack4(a1[it]);
            BsW[(it + 4) * (16 * BK / 4)] = pack4(b1[it]);
        }
        __syncthreads();

        // ---- compute ----
        i32x4 af[4], bf[4];
#pragma unroll
        for (int i = 0; i < 4; ++i)
            af[i] = *(const i32x4*)&As[(mrow + i * 16) * BK + kq];
#pragma unroll
        for (int j = 0; j < 4; ++j)
            bf[j] = *(const i32x4*)&Bs[(nrow + j * 16) * BK + kq];

#pragma unroll
        for (int i = 0; i < 4; ++i)
#pragma unroll
            for (int j = 0; j < 4; ++j)
                acc[i][j] = __builtin_amdgcn_mfma_i32_16x16x64_i8(af[i], bf[j], acc[i][j], 0, 0, 0);
    }

    // Epilogue. C/D layout: col = lane&15, row = (lane>>4)*4 + reg
    const int col16 = lane & 15;
    const int rquad = (lane >> 4) * 4;
#pragma unroll
    for (int j = 0; j < 4; ++j) {
        const int col = bn * BN + wn * 64 + j * 16 + col16;
        // match np ref arithmetic exactly: (0.05f * ws) / 0.1f, all f32
        float s = 0.05f * wscale[col];
        s = s / 0.1f;
        const float bz = (float)bias[col];
#pragma unroll
        for (int i = 0; i < 4; ++i) {
            const int row0 = bm * BM + wm * 64 + i * 16 + rquad;
#pragma unroll
            for (int r = 0; r < 4; ++r) {
                float v = ((float)acc[i][j][r] + bz) * s;
                v = rintf(v);                          // RTNE, matches np.round
                v = fminf(fmaxf(v, -128.0f), 127.0f);
                C[(size_t)(row0 + r) * N_DIM + col] = (int)v;
            }
        }
    }
}

extern "C" void kernel_launch(void* const* d_in, const int* in_sizes, int n_in,
                              void* d_out, int out_size, void* d_ws, size_t ws_size,
                              hipStream_t stream) {
    const int*   x32    = (const int*)d_in[0];     // int8 values promoted to int32
    const int*   w32    = (const int*)d_in[1];
    const int*   bias   = (const int*)d_in[2];
    const float* wscale = (const float*)d_in[3];
    int*         out    = (int*)d_out;

    // Single fused kernel: no pack pass, no workspace use.
    dim3 grid(N_DIM / BN, M_DIM / BM);   // (32, 64)
    qgemm_fused_kernel<<<grid, 256, 0, stream>>>(x32, w32, bias, wscale, out);
}

// Round 3
// 457.926 us; speedup vs baseline: 1.4839x; 1.4839x over previous
//
#include <hip/hip_runtime.h>
#include <cstdint>
#include <cstddef>

// Problem constants
#define M_DIM 8192
#define N_DIM 4096
#define K_DIM 4096

#define BM 128
#define BN 128
#define BK 64   // int8 elements per K-step (64 bytes per LDS row)

using i32x4  = __attribute__((ext_vector_type(4))) int;
using i32x16 = __attribute__((ext_vector_type(16))) int;

__device__ __forceinline__ void async_load16(const void* g, void* l) {
    __builtin_amdgcn_global_load_lds(
        (const __attribute__((address_space(1))) void*)g,
        (__attribute__((address_space(3))) void*)l,
        16, 0, 0);
}

// Pack int32 values (range [-128,127]) to int8, both buffers in one launch.
// Lane l reads int4 at [base + l + 256*j] (16B/lane contiguous per instr),
// writes one packed dword at the same linear index (4B/lane contiguous).
// Blocks [0, nxblocks) cover x; the rest cover w. 1024 int4s per block.
__global__ __launch_bounds__(256) void pack_i8_kernel(const int4* __restrict__ xsrc,
                                                      int* __restrict__ xdst,
                                                      const int4* __restrict__ wsrc,
                                                      int* __restrict__ wdst,
                                                      int nxblocks) {
    const bool isw = (int)blockIdx.x >= nxblocks;
    const int4* src = isw ? wsrc : xsrc;
    int*       dst  = isw ? wdst : xdst;
    const long bb   = isw ? ((long)blockIdx.x - nxblocks) : (long)blockIdx.x;
    const long base = bb * 1024 + threadIdx.x;
#pragma unroll
    for (int j = 0; j < 4; ++j) {
        const long i = base + 256 * j;
        const int4 v = src[i];
        dst[i] = (v.x & 0xff) | ((v.y & 0xff) << 8) | ((v.z & 0xff) << 16) | (v.w << 24);
    }
}

// C[m][n] = sum_k A[m][k]*B[n][k]  (both K-contiguous, int8), then
// out = clamp(round((acc + bias[n]) * (0.05*wscale[n]/0.1)), -128, 127) as int32.
// 32x32x32 i8 MFMA. LDS tiles are chunk-XOR-swizzled: LDS[row][c] holds global
// 16B-chunk (c ^ (row&3)) of that row. Staging applies the XOR on the per-lane
// GLOBAL source address (global_load_lds dest must stay linear, rule 21); the
// fragment read applies the same XOR -> slot map (4r + (q^(r&3)))%8 is uniform
// (8 lanes/slot), i.e. conflict-free ds_read_b128.
__global__ __launch_bounds__(256) void qgemm_i8_kernel(const int8_t* __restrict__ A,
                                                       const int8_t* __restrict__ B,
                                                       const int* __restrict__ bias,
                                                       const float* __restrict__ wscale,
                                                       int* __restrict__ C) {
    __shared__ int8_t As[BM * BK];   // 8 KiB, row-major 128 x 64B (swizzled chunks)
    __shared__ int8_t Bs[BN * BK];   // 8 KiB

    const int tid  = threadIdx.x;
    const int wave = tid >> 6;
    const int lane = tid & 63;
    const int bm = blockIdx.y;
    const int bn = blockIdx.x;

    const int8_t* Ab = A + (size_t)bm * BM * K_DIM;
    const int8_t* Bb = B + (size_t)bn * BN * K_DIM;

    const int wm = wave >> 1;   // 0..1 : row half of tile
    const int wn = wave & 1;    // 0..1 : col half of tile

    i32x16 acc[2][2] = {};

    // staging geometry: each wave-issue covers 16 rows x 64B = 1 KiB linear LDS.
    // dest (linear): row = lane>>2, chunk = lane&3. source chunk XOR'd by row&3.
    const int srow = lane >> 2;                          // 0..15
    const int sxor = ((lane & 3) ^ (srow & 3)) * 16;     // swizzled 16B source chunk

    // fragment geometry (32x32x32): A/B lane layout: row = lane&31,
    // k-bytes = (lane>>5)*16 within each 32B k-slice.
    const int l31 = lane & 31;
    const int khi = lane >> 5;   // 0..1
    const int x3  = lane & 3;    // == row&3 for all fragment rows (offsets are %4==0)
    const int arow = wm * 64 + l31;
    const int brow = wn * 64 + l31;

    for (int kt = 0; kt < K_DIM; kt += BK) {
#pragma unroll
        for (int c = 0; c < 2; ++c) {
            const int rbase = (c * 4 + wave) * 16;
            async_load16(Ab + (size_t)(rbase + srow) * K_DIM + kt + sxor,
                         &As[(c * 4 + wave) * 1024]);
            async_load16(Bb + (size_t)(rbase + srow) * K_DIM + kt + sxor,
                         &Bs[(c * 4 + wave) * 1024]);
        }
        __syncthreads();

        i32x4 af[2][2], bf[2][2];   // [m or n block][kk]
#pragma unroll
        for (int i = 0; i < 2; ++i)
#pragma unroll
            for (int kk = 0; kk < 2; ++kk) {
                const int q = (kk << 1) | khi;           // global 16B chunk index
                af[i][kk] = *(const i32x4*)&As[(arow + i * 32) * BK + ((q ^ x3) * 16)];
                bf[i][kk] = *(const i32x4*)&Bs[(brow + i * 32) * BK + ((q ^ x3) * 16)];
            }

#pragma unroll
        for (int i = 0; i < 2; ++i)
#pragma unroll
            for (int j = 0; j < 2; ++j)
#pragma unroll
                for (int kk = 0; kk < 2; ++kk)
                    acc[i][j] = __builtin_amdgcn_mfma_i32_32x32x32_i8(af[i][kk], bf[j][kk],
                                                                      acc[i][j], 0, 0, 0);

        __syncthreads();
    }

    // Epilogue. 32x32 C/D layout: col = lane&31, row = (reg&3) + 8*(reg>>2) + 4*(lane>>5)
    const int lrow4 = khi * 4;
#pragma unroll
    for (int j = 0; j < 2; ++j) {
        const int col = bn * BN + wn * 64 + j * 32 + l31;
        // match np ref arithmetic exactly: (0.05f * ws) / 0.1f, all f32
        float s = 0.05f * wscale[col];
        s = s / 0.1f;
        const float bz = (float)bias[col];
#pragma unroll
        for (int i = 0; i < 2; ++i) {
            const int row0 = bm * BM + wm * 64 + i * 32 + lrow4;
#pragma unroll
            for (int r = 0; r < 16; ++r) {
                const int row = row0 + (r & 3) + 8 * (r >> 2);
                float v = ((float)acc[i][j][r] + bz) * s;
                v = rintf(v);                          // RTNE, matches np.round
                v = fminf(fmaxf(v, -128.0f), 127.0f);
                C[(size_t)row * N_DIM + col] = (int)v;
            }
        }
    }
}

extern "C" void kernel_launch(void* const* d_in, const int* in_sizes, int n_in,
                              void* d_out, int out_size, void* d_ws, size_t ws_size,
                              hipStream_t stream) {
    const int*   x32    = (const int*)d_in[0];     // int8 values promoted to int32
    const int*   w32    = (const int*)d_in[1];
    const int*   bias   = (const int*)d_in[2];
    const float* wscale = (const float*)d_in[3];
    int*         out    = (int*)d_out;

    int8_t* xp = (int8_t*)d_ws;                         // 32 MiB packed x
    int8_t* wp = xp + (size_t)M_DIM * K_DIM;            // 16 MiB packed w

    {
        const int nxblocks = (int)((long)M_DIM * K_DIM / 4 / 1024);   // 8192
        const int nwblocks = (int)((long)N_DIM * K_DIM / 4 / 1024);   // 4096
        pack_i8_kernel<<<nxblocks + nwblocks, 256, 0, stream>>>(
            (const int4*)x32, (int*)xp, (const int4*)w32, (int*)wp, nxblocks);
    }

    dim3 grid(N_DIM / BN, M_DIM / BM);   // (32, 64)
    qgemm_i8_kernel<<<grid, 256, 0, stream>>>(xp, wp, bias, wscale, out);
}

// Round 4
// 437.229 us; speedup vs baseline: 1.5541x; 1.0473x over previous
//
#include <hip/hip_runtime.h>
#include <cstdint>
#include <cstddef>

// Problem constants
#define M_DIM 8192
#define N_DIM 4096
#define K_DIM 4096

#define BM 128
#define BN 128
#define BK 64   // int8 elements per K-step (64 bytes per LDS row)

using i32x4 = __attribute__((ext_vector_type(4))) int;

__device__ __forceinline__ void async_load16(const void* g, void* l) {
    __builtin_amdgcn_global_load_lds(
        (const __attribute__((address_space(1))) void*)g,
        (__attribute__((address_space(3))) void*)l,
        16, 0, 0);
}

// Pack int32 values (range [-128,127]) to int8, both buffers in one launch.
// Lane l reads int4 at [base + l + 256*j] (16B/lane contiguous per instr),
// writes one packed dword at the same linear index (4B/lane contiguous).
// Blocks [0, nxblocks) cover x; the rest cover w. 1024 int4s per block.
__global__ __launch_bounds__(256) void pack_i8_kernel(const int4* __restrict__ xsrc,
                                                      int* __restrict__ xdst,
                                                      const int4* __restrict__ wsrc,
                                                      int* __restrict__ wdst,
                                                      int nxblocks) {
    const bool isw = (int)blockIdx.x >= nxblocks;
    const int4* src = isw ? wsrc : xsrc;
    int*       dst  = isw ? wdst : xdst;
    const long bb   = isw ? ((long)blockIdx.x - nxblocks) : (long)blockIdx.x;
    const long base = bb * 1024 + threadIdx.x;
#pragma unroll
    for (int j = 0; j < 4; ++j) {
        const long i = base + 256 * j;
        const int4 v = src[i];
        dst[i] = (v.x & 0xff) | ((v.y & 0xff) << 8) | ((v.z & 0xff) << 16) | (v.w << 24);
    }
}

// C[m][n] = sum_k A[m][k]*B[n][k]  (both K-contiguous, int8), then
// out = clamp(round((acc + bias[n]) * (0.05*wscale[n]/0.1)), -128, 127) as int32.
//
// T3/T4 minimum 2-phase double-buffer: stage tile t+1 into buf^1 BEFORE the
// ds_read+MFMA of tile t, single __syncthreads per K-step (its vmcnt(0) drain
// lands on loads issued a full compute phase earlier). Fragment/staging/epilogue
// geometry identical to the verified 16x16x64 kernel (absmax 0 in r0/r1).
__global__ __launch_bounds__(256) void qgemm_i8_kernel(const int8_t* __restrict__ A,
                                                       const int8_t* __restrict__ B,
                                                       const int* __restrict__ bias,
                                                       const float* __restrict__ wscale,
                                                       int* __restrict__ C) {
    __shared__ int8_t As[2][BM * BK];   // 2 x 8 KiB, row-major 128 x 64B
    __shared__ int8_t Bs[2][BN * BK];   // 2 x 8 KiB

    const int tid  = threadIdx.x;
    const int wave = tid >> 6;
    const int lane = tid & 63;
    const int bm = blockIdx.y;
    const int bn = blockIdx.x;

    const int8_t* Ab = A + (size_t)bm * BM * K_DIM;
    const int8_t* Bb = B + (size_t)bn * BN * K_DIM;

    const int wm = wave >> 1;   // 0..1 : row half of tile
    const int wn = wave & 1;    // 0..1 : col half of tile

    i32x4 acc[4][4] = {};

    // staging geometry: each wave-issue covers 16 rows x 64B = 1 KiB linear LDS
    const int srow = lane >> 2;          // 0..15
    const int scol = (lane & 3) * 16;    // 0/16/32/48

    // fragment geometry
    const int kq   = (lane >> 4) * 16;       // byte offset in 64B row
    const int mrow = wm * 64 + (lane & 15);
    const int nrow = wn * 64 + (lane & 15);

    // ---- prologue: stage tile 0 into buf 0, drain, barrier ----
#pragma unroll
    for (int c = 0; c < 2; ++c) {
        const int rbase = (c * 4 + wave) * 16;
        async_load16(Ab + (size_t)(rbase + srow) * K_DIM + 0 + scol,
                     &As[0][(c * 4 + wave) * 1024]);
        async_load16(Bb + (size_t)(rbase + srow) * K_DIM + 0 + scol,
                     &Bs[0][(c * 4 + wave) * 1024]);
    }
    __syncthreads();

    int cur = 0;
    for (int kt = 0; kt < K_DIM; kt += BK) {
        // ---- issue next tile's stage into the other buffer (no wait) ----
        if (kt + BK < K_DIM) {
#pragma unroll
            for (int c = 0; c < 2; ++c) {
                const int rbase = (c * 4 + wave) * 16;
                async_load16(Ab + (size_t)(rbase + srow) * K_DIM + (kt + BK) + scol,
                             &As[cur ^ 1][(c * 4 + wave) * 1024]);
                async_load16(Bb + (size_t)(rbase + srow) * K_DIM + (kt + BK) + scol,
                             &Bs[cur ^ 1][(c * 4 + wave) * 1024]);
            }
        }

        // ---- compute current tile ----
        i32x4 af[4], bf[4];
#pragma unroll
        for (int i = 0; i < 4; ++i)
            af[i] = *(const i32x4*)&As[cur][(mrow + i * 16) * BK + kq];
#pragma unroll
        for (int j = 0; j < 4; ++j)
            bf[j] = *(const i32x4*)&Bs[cur][(nrow + j * 16) * BK + kq];

#pragma unroll
        for (int i = 0; i < 4; ++i)
#pragma unroll
            for (int j = 0; j < 4; ++j)
                acc[i][j] = __builtin_amdgcn_mfma_i32_16x16x64_i8(af[i], bf[j], acc[i][j], 0, 0, 0);

        // one barrier per K-step: drains vmcnt(0) on loads issued ABOVE the
        // compute (full MFMA phase of latency cover), plus lgkm + barrier.
        __syncthreads();
        cur ^= 1;
    }

    // Epilogue. C/D layout: col = lane&15, row = (lane>>4)*4 + reg
    const int col16 = lane & 15;
    const int rquad = (lane >> 4) * 4;
#pragma unroll
    for (int j = 0; j < 4; ++j) {
        const int col = bn * BN + wn * 64 + j * 16 + col16;
        // match np ref arithmetic exactly: (0.05f * ws) / 0.1f, all f32
        float s = 0.05f * wscale[col];
        s = s / 0.1f;
        const float bz = (float)bias[col];
#pragma unroll
        for (int i = 0; i < 4; ++i) {
            const int row0 = bm * BM + wm * 64 + i * 16 + rquad;
#pragma unroll
            for (int r = 0; r < 4; ++r) {
                float v = ((float)acc[i][j][r] + bz) * s;
                v = rintf(v);                          // RTNE, matches np.round
                v = fminf(fmaxf(v, -128.0f), 127.0f);
                C[(size_t)(row0 + r) * N_DIM + col] = (int)v;
            }
        }
    }
}

extern "C" void kernel_launch(void* const* d_in, const int* in_sizes, int n_in,
                              void* d_out, int out_size, void* d_ws, size_t ws_size,
                              hipStream_t stream) {
    const int*   x32    = (const int*)d_in[0];     // int8 values promoted to int32
    const int*   w32    = (const int*)d_in[1];
    const int*   bias   = (const int*)d_in[2];
    const float* wscale = (const float*)d_in[3];
    int*         out    = (int*)d_out;

    int8_t* xp = (int8_t*)d_ws;                         // 32 MiB packed x
    int8_t* wp = xp + (size_t)M_DIM * K_DIM;            // 16 MiB packed w

    {
        const int nxblocks = (int)((long)M_DIM * K_DIM / 4 / 1024);   // 8192
        const int nwblocks = (int)((long)N_DIM * K_DIM / 4 / 1024);   // 4096
        pack_i8_kernel<<<nxblocks + nwblocks, 256, 0, stream>>>(
            (const int4*)x32, (int*)xp, (const int4*)w32, (int*)wp, nxblocks);
    }

    dim3 grid(N_DIM / BN, M_DIM / BM);   // (32, 64)
    qgemm_i8_kernel<<<grid, 256, 0, stream>>>(xp, wp, bias, wscale, out);
}

// Round 5
// 407.423 us; speedup vs baseline: 1.6678x; 1.0732x over previous
//
#include <hip/hip_runtime.h>
#include <cstdint>
#include <cstddef>

// Problem constants
#define M_DIM 8192
#define N_DIM 4096
#define K_DIM 4096

#define BM 256
#define BN 256
// K-tile = 128 bytes of K per row; 2 K-tiles per iteration; 4096/256 = 16 iters.

using i32x4 = __attribute__((ext_vector_type(4))) int;

__device__ __forceinline__ void async_load16(const void* g, void* l) {
    __builtin_amdgcn_global_load_lds(
        (const __attribute__((address_space(1))) void*)g,
        (__attribute__((address_space(3))) void*)l,
        16, 0, 0);
}

// Pack int32 values (range [-128,127]) to int8, both buffers in one launch.
__global__ __launch_bounds__(256) void pack_i8_kernel(const int4* __restrict__ xsrc,
                                                      int* __restrict__ xdst,
                                                      const int4* __restrict__ wsrc,
                                                      int* __restrict__ wdst,
                                                      int nxblocks) {
    const bool isw = (int)blockIdx.x >= nxblocks;
    const int4* src = isw ? wsrc : xsrc;
    int*       dst  = isw ? wdst : xdst;
    const long bb   = isw ? ((long)blockIdx.x - nxblocks) : (long)blockIdx.x;
    const long base = bb * 1024 + threadIdx.x;
#pragma unroll
    for (int j = 0; j < 4; ++j) {
        const long i = base + 256 * j;
        const int4 v = src[i];
        dst[i] = (v.x & 0xff) | ((v.y & 0xff) << 8) | ((v.z & 0xff) << 16) | (v.w << 24);
    }
}

// 256x256-tile 8-phase i8 GEMM (T2+T3+T4+T5 port of the bf16 template).
// LDS map (128 KiB): A: buf*32768 + half*16384 + row*128 (rows 0..127 per half)
//                    B: 65536 + same. 16B chunks XOR-swizzled by (row&7):
// LDS[row][c] holds global chunk (c ^ (row&7)); staging pre-swizzles the global
// source (linear LDS dest, rule 21); ds_read applies the same XOR.
__global__ __launch_bounds__(512, 2) void qgemm_i8_kernel(const int8_t* __restrict__ A,
                                                          const int8_t* __restrict__ B,
                                                          const int* __restrict__ bias,
                                                          const float* __restrict__ wscale,
                                                          int* __restrict__ C) {
    __shared__ int8_t LDS[131072];

    const int tid  = threadIdx.x;
    const int wave = tid >> 6;
    const int lane = tid & 63;
    const int wm = wave >> 2;   // 0..1
    const int wn = wave & 3;    // 0..3
    const int bm = blockIdx.y;
    const int bn = blockIdx.x;

    const int8_t* Ab = A + (size_t)bm * BM * K_DIM;
    const int8_t* Bb = B + (size_t)bn * BN * K_DIM;

    // Staging: per phase each wave issues 2 global_load_lds covering 16 rows
    // (2 groups of 8 rows x 128B). Lane l -> row +(l>>3), chunk (l&7)^(l>>3)
    // (row&7 == l>>3 since all row bases are multiples of 8/16).
    const int l8 = lane >> 3;
    const int l7 = lane & 7;
    const int8_t* Ag = Ab + (size_t)(wave * 16 + l8) * K_DIM + ((l7 ^ l8) * 16);
    const int8_t* Bg = Bb + (size_t)(wave * 16 + l8) * K_DIM + ((l7 ^ l8) * 16);
    const int sdst = wave * 2048;

    // Fragment ds_read bases. A row = mh*128 + wm*64 + mi*16 + (lane&15);
    // chunk = (kk*4 + (lane>>4)) ^ (row&7); row&7 == lane&7. kk=1 addr = kk=0 ^ 64.
    const int l15 = lane & 15;
    const int qh  = lane >> 4;
    const int a_off0 = wm * 8192 + l15 * 128 + ((qh ^ l7) * 16);
    const int a_off1 = a_off0 ^ 64;
    const int b_off0 = 65536 + wn * 4096 + l15 * 128 + ((qh ^ l7) * 16);
    const int b_off1 = b_off0 ^ 64;

    i32x4 acc[4][4][2] = {};   // [quadrant][mi][ni]

#define ISSUE_HT(GB, REG, BUF, HH, T) do { \
    async_load16((GB) + (size_t)((HH) * 128)     * K_DIM + (size_t)(T) * 128, \
                 &LDS[(REG) + (BUF) * 32768 + (HH) * 16384 + sdst]); \
    async_load16((GB) + (size_t)((HH) * 128 + 8) * K_DIM + (size_t)(T) * 128, \
                 &LDS[(REG) + (BUF) * 32768 + (HH) * 16384 + sdst + 1024]); \
} while (0)

#define PHASE(BUF, MH, NH, QD, ISSUES, CHK) do { \
    i32x4 af[4][2]; i32x4 bf[2][2]; \
    _Pragma("unroll") \
    for (int mi = 0; mi < 4; ++mi) { \
        af[mi][0] = *(const i32x4*)&LDS[a_off0 + (BUF) * 32768 + (MH) * 16384 + mi * 2048]; \
        af[mi][1] = *(const i32x4*)&LDS[a_off1 + (BUF) * 32768 + (MH) * 16384 + mi * 2048]; \
    } \
    _Pragma("unroll") \
    for (int ni = 0; ni < 2; ++ni) { \
        bf[ni][0] = *(const i32x4*)&LDS[b_off0 + (BUF) * 32768 + (NH) * 16384 + ni * 2048]; \
        bf[ni][1] = *(const i32x4*)&LDS[b_off1 + (BUF) * 32768 + (NH) * 16384 + ni * 2048]; \
    } \
    ISSUES; \
    CHK; \
    __builtin_amdgcn_s_barrier(); \
    asm volatile("s_waitcnt lgkmcnt(0)" ::: "memory"); \
    __builtin_amdgcn_sched_barrier(0); \
    __builtin_amdgcn_s_setprio(1); \
    _Pragma("unroll") \
    for (int mi = 0; mi < 4; ++mi) { \
        _Pragma("unroll") \
        for (int ni = 0; ni < 2; ++ni) { \
            acc[QD][mi][ni] = __builtin_amdgcn_mfma_i32_16x16x64_i8(af[mi][0], bf[ni][0], acc[QD][mi][ni], 0, 0, 0); \
            acc[QD][mi][ni] = __builtin_amdgcn_mfma_i32_16x16x64_i8(af[mi][1], bf[ni][1], acc[QD][mi][ni], 0, 0, 0); \
        } \
    } \
    __builtin_amdgcn_s_setprio(0); \
    __builtin_amdgcn_s_barrier(); \
} while (0)

    // ---- prologue: establish steady-state issue FIFO ----
    // order: B0(0), A1(0), A0(0), B1(0), B0(1), A1(1); vmcnt(4) -> tile0 landed.
    ISSUE_HT(Bg, 65536, 0, 0, 0);
    ISSUE_HT(Ag, 0,     0, 1, 0);
    ISSUE_HT(Ag, 0,     0, 0, 0);
    ISSUE_HT(Bg, 65536, 0, 1, 0);
    ISSUE_HT(Bg, 65536, 1, 0, 1);
    ISSUE_HT(Ag, 0,     1, 1, 1);
    asm volatile("s_waitcnt vmcnt(4)" ::: "memory");
    __builtin_amdgcn_s_barrier();

    // ---- main loop: iter i computes tiles U=2i (buf0, P1-4) and V=2i+1 (buf1, P5-8).
    // Quadrants per half-iter: P1=(0,0) P2=(1,0) P3=(1,1) P4=(0,1) so each phase
    // group-wide touches only halves (mh, nh) -> half-tile prefetch windows hold.
    for (int i = 0; i < 16; ++i) {
        const int V = 2 * i + 1;
        const int W = 2 * i + 2;   // -> buf0
        const int X = 2 * i + 3;   // -> buf1
        const bool more = (i < 15);

        PHASE(0, 0, 0, 0, { ISSUE_HT(Ag, 0,     1, 0, V); }, {});
        PHASE(0, 1, 0, 1, { ISSUE_HT(Bg, 65536, 1, 1, V); }, {});
        PHASE(0, 1, 1, 2, { if (more) ISSUE_HT(Bg, 65536, 0, 0, W); }, {});
        PHASE(0, 0, 1, 3, { if (more) ISSUE_HT(Ag, 0,     0, 1, W); },
              { if (more) { asm volatile("s_waitcnt vmcnt(4)" ::: "memory"); }
                else      { asm volatile("s_waitcnt vmcnt(0)" ::: "memory"); } });
        PHASE(1, 0, 0, 0, { if (more) ISSUE_HT(Ag, 0,     0, 0, W); }, {});
        PHASE(1, 1, 0, 1, { if (more) ISSUE_HT(Bg, 65536, 0, 1, W); }, {});
        PHASE(1, 1, 1, 2, { if (more) ISSUE_HT(Bg, 65536, 1, 0, X); }, {});
        PHASE(1, 0, 1, 3, { if (more) ISSUE_HT(Ag, 0,     1, 1, X); },
              { if (more) { asm volatile("s_waitcnt vmcnt(4)" ::: "memory"); } });
    }

#undef PHASE
#undef ISSUE_HT

    // ---- epilogue. C/D layout (verified): col = lane&15, row = (lane>>4)*4 + reg.
    const int col16 = lane & 15;
    const int rquad = (lane >> 4) * 4;
#pragma unroll
    for (int qd = 0; qd < 4; ++qd) {
        const int mh = (qd & 1) ^ (qd >> 1);   // 0,1,1,0
        const int nh = qd >> 1;                // 0,0,1,1
#pragma unroll
        for (int ni = 0; ni < 2; ++ni) {
            const int col = bn * BN + nh * 128 + wn * 32 + ni * 16 + col16;
            // match np ref arithmetic exactly: (0.05f * ws) / 0.1f, all f32
            float s = 0.05f * wscale[col];
            s = s / 0.1f;
            const float bz = (float)bias[col];
#pragma unroll
            for (int mi = 0; mi < 4; ++mi) {
                const int row0 = bm * BM + mh * 128 + wm * 64 + mi * 16 + rquad;
#pragma unroll
                for (int r = 0; r < 4; ++r) {
                    float v = ((float)acc[qd][mi][ni][r] + bz) * s;
                    v = rintf(v);                          // RTNE, matches np.round
                    v = fminf(fmaxf(v, -128.0f), 127.0f);
                    C[(size_t)(row0 + r) * N_DIM + col] = (int)v;
                }
            }
        }
    }
}

extern "C" void kernel_launch(void* const* d_in, const int* in_sizes, int n_in,
                              void* d_out, int out_size, void* d_ws, size_t ws_size,
                              hipStream_t stream) {
    const int*   x32    = (const int*)d_in[0];     // int8 values promoted to int32
    const int*   w32    = (const int*)d_in[1];
    const int*   bias   = (const int*)d_in[2];
    const float* wscale = (const float*)d_in[3];
    int*         out    = (int*)d_out;

    int8_t* xp = (int8_t*)d_ws;                         // 32 MiB packed x
    int8_t* wp = xp + (size_t)M_DIM * K_DIM;            // 16 MiB packed w

    {
        const int nxblocks = (int)((long)M_DIM * K_DIM / 4 / 1024);   // 8192
        const int nwblocks = (int)((long)N_DIM * K_DIM / 4 / 1024);   // 4096
        pack_i8_kernel<<<nxblocks + nwblocks, 256, 0, stream>>>(
            (const int4*)x32, (int*)xp, (const int4*)w32, (int*)wp, nxblocks);
    }

    dim3 grid(N_DIM / BN, M_DIM / BM);   // (16, 32)
    qgemm_i8_kernel<<<grid, 512, 0, stream>>>(xp, wp, bias, wscale, out);
}

// Round 6
// 389.702 us; speedup vs baseline: 1.7436x; 1.0455x over previous
//
#include <hip/hip_runtime.h>
#include <cstdint>
#include <cstddef>

// Problem constants
#define M_DIM 8192
#define N_DIM 4096
#define K_DIM 4096

#define BM 256
#define BN 256
// K-tile = 128 bytes of K per row; 2 K-tiles per iteration; 4096/256 = 16 iters.

using i32x4 = __attribute__((ext_vector_type(4))) int;

__device__ __forceinline__ void async_load16(const void* g, void* l) {
    __builtin_amdgcn_global_load_lds(
        (const __attribute__((address_space(1))) void*)g,
        (__attribute__((address_space(3))) void*)l,
        16, 0, 0);
}

// Pack int32 values (range [-128,127]) to int8, both buffers in one launch.
__global__ __launch_bounds__(256) void pack_i8_kernel(const int4* __restrict__ xsrc,
                                                      int* __restrict__ xdst,
                                                      const int4* __restrict__ wsrc,
                                                      int* __restrict__ wdst,
                                                      int nxblocks) {
    const bool isw = (int)blockIdx.x >= nxblocks;
    const int4* src = isw ? wsrc : xsrc;
    int*       dst  = isw ? wdst : xdst;
    const long bb   = isw ? ((long)blockIdx.x - nxblocks) : (long)blockIdx.x;
    const long base = bb * 1024 + threadIdx.x;
#pragma unroll
    for (int j = 0; j < 4; ++j) {
        const long i = base + 256 * j;
        const int4 v = src[i];
        dst[i] = (v.x & 0xff) | ((v.y & 0xff) << 8) | ((v.z & 0xff) << 16) | (v.w << 24);
    }
}

// 256x256-tile 8-phase i8 GEMM. Gray-code quadrant order (0,0)->(0,1)->(1,1)->(1,0)
// holds the unchanged operand's fragments in registers across phases, cutting
// ds_read_b128 from 48 to 28 per K-tile (the r5 kernel was LDS-read-BW-bound:
// 96KB/CU/phase at ~256 B/cyc == measured 378 cyc/phase).
// LDS map (128 KiB): A: buf*32768 + half*16384 + row*128; B: +65536.
// 16B chunks XOR-swizzled by (row&7) via pre-swizzled global source (rule 21).
__global__ __launch_bounds__(512, 2) void qgemm_i8_kernel(const int8_t* __restrict__ A,
                                                          const int8_t* __restrict__ B,
                                                          const int* __restrict__ bias,
                                                          const float* __restrict__ wscale,
                                                          int* __restrict__ C) {
    __shared__ int8_t LDS[131072];

    const int tid  = threadIdx.x;
    const int wave = tid >> 6;
    const int lane = tid & 63;
    const int wm = wave >> 2;   // 0..1
    const int wn = wave & 3;    // 0..3
    const int bm = blockIdx.y;
    const int bn = blockIdx.x;

    const int8_t* Ab = A + (size_t)bm * BM * K_DIM;
    const int8_t* Bb = B + (size_t)bn * BN * K_DIM;

    // Staging: per ISSUE_HT a wave covers 16 rows x 128B (2 x global_load_lds).
    // Lane l -> row +(l>>3), source chunk (l&7)^(l>>3) (pre-swizzled global).
    const int l8 = lane >> 3;
    const int l7 = lane & 7;
    const int8_t* Ag = Ab + (size_t)(wave * 16 + l8) * K_DIM + ((l7 ^ l8) * 16);
    const int8_t* Bg = Bb + (size_t)(wave * 16 + l8) * K_DIM + ((l7 ^ l8) * 16);
    const int sdst = wave * 2048;

    // Fragment ds_read bases. A row = mh*128 + wm*64 + mi*16 + (lane&15);
    // chunk = (kk*4 + (lane>>4)) ^ (row&7); row&7 == lane&7. kk=1 addr = kk=0 ^ 64.
    const int l15 = lane & 15;
    const int qh  = lane >> 4;
    const int a_off0 = wm * 8192 + l15 * 128 + ((qh ^ l7) * 16);
    const int a_off1 = a_off0 ^ 64;
    const int b_off0 = 65536 + wn * 4096 + l15 * 128 + ((qh ^ l7) * 16);
    const int b_off1 = b_off0 ^ 64;

    i32x4 acc[4][4][2] = {};   // [quadrant][mi][ni]
    i32x4 af[4][2];            // current A-half fragments (held across phases)
    i32x4 bf[2][2];            // current B-half fragments (held across phases)

#define ISSUE_HT(GB, REG, BUF, HH, T) do { \
    async_load16((GB) + (size_t)((HH) * 128)     * K_DIM + (size_t)(T) * 128, \
                 &LDS[(REG) + (BUF) * 32768 + (HH) * 16384 + sdst]); \
    async_load16((GB) + (size_t)((HH) * 128 + 8) * K_DIM + (size_t)(T) * 128, \
                 &LDS[(REG) + (BUF) * 32768 + (HH) * 16384 + sdst + 1024]); \
} while (0)

#define LOAD_AF(BUF, MH) do { \
    _Pragma("unroll") \
    for (int mi = 0; mi < 4; ++mi) { \
        af[mi][0] = *(const i32x4*)&LDS[a_off0 + (BUF) * 32768 + (MH) * 16384 + mi * 2048]; \
        af[mi][1] = *(const i32x4*)&LDS[a_off1 + (BUF) * 32768 + (MH) * 16384 + mi * 2048]; \
    } \
} while (0)

#define LOAD_BF(BUF, NH) do { \
    _Pragma("unroll") \
    for (int ni = 0; ni < 2; ++ni) { \
        bf[ni][0] = *(const i32x4*)&LDS[b_off0 + (BUF) * 32768 + (NH) * 16384 + ni * 2048]; \
        bf[ni][1] = *(const i32x4*)&LDS[b_off1 + (BUF) * 32768 + (NH) * 16384 + ni * 2048]; \
    } \
} while (0)

#define VM6 asm volatile("s_waitcnt vmcnt(6)" ::: "memory")
#define VM0 asm volatile("s_waitcnt vmcnt(0)" ::: "memory")

#define PHASE(LOADS, QD, ISSUES, CHK) do { \
    LOADS; \
    ISSUES; \
    CHK; \
    __builtin_amdgcn_s_barrier(); \
    asm volatile("s_waitcnt lgkmcnt(0)" ::: "memory"); \
    __builtin_amdgcn_sched_barrier(0); \
    __builtin_amdgcn_s_setprio(1); \
    _Pragma("unroll") \
    for (int mi = 0; mi < 4; ++mi) { \
        _Pragma("unroll") \
        for (int ni = 0; ni < 2; ++ni) { \
            acc[QD][mi][ni] = __builtin_amdgcn_mfma_i32_16x16x64_i8(af[mi][0], bf[ni][0], acc[QD][mi][ni], 0, 0, 0); \
            acc[QD][mi][ni] = __builtin_amdgcn_mfma_i32_16x16x64_i8(af[mi][1], bf[ni][1], acc[QD][mi][ni], 0, 0, 0); \
        } \
    } \
    __builtin_amdgcn_s_setprio(0); \
    __builtin_amdgcn_s_barrier(); \
} while (0)

    // ---- prologue: tile0 fully + tile1 partial (A1h0, B1h1, A1h1).
    // B1h0(t1) is issued at P1 of iter 0. vmcnt(10) -> A0h0,B0h0 landed.
    ISSUE_HT(Ag, 0,     0, 0, 0);   // #1 A0h0
    ISSUE_HT(Bg, 65536, 0, 0, 0);   // #2 B0h0
    ISSUE_HT(Bg, 65536, 0, 1, 0);   // #3 B0h1
    ISSUE_HT(Ag, 0,     0, 1, 0);   // #4 A0h1
    ISSUE_HT(Ag, 0,     1, 0, 1);   // #5 A1h0
    ISSUE_HT(Bg, 65536, 1, 1, 1);   // #6 B1h1
    ISSUE_HT(Ag, 0,     1, 1, 1);   // #7 A1h1
    asm volatile("s_waitcnt vmcnt(10)" ::: "memory");
    __builtin_amdgcn_s_barrier();

    // ---- main loop. Iter i: tiles U=2i (buf0, P1-4), V=2i+1 (buf1, P5-8).
    // Quadrants: P1=(0,0) P2=(0,1) P3=(1,1) P4=(1,0); loads only the changed half.
    // vmcnt(6) each phase => issues >=3 phases old have landed (FIFO-traced).
    // Region overwrites sit >=2 barriers after that region's last ds_read.
    for (int i = 0; i < 16; ++i) {
        const int V = 2 * i + 1;
        const int W = 2 * i + 2;   // -> buf0
        const int X = 2 * i + 3;   // -> buf1
        const bool more = (i < 15);

        PHASE({ LOAD_AF(0, 0); LOAD_BF(0, 0); }, 0,
              { ISSUE_HT(Bg, 65536, 1, 0, V); }, VM6);
        PHASE({ LOAD_BF(0, 1); }, 1,
              { if (more) ISSUE_HT(Ag, 0,     0, 0, W); }, VM6);
        PHASE({ LOAD_AF(0, 1); }, 2,
              { if (more) ISSUE_HT(Bg, 65536, 0, 1, W); }, VM6);
        PHASE({ LOAD_BF(0, 0); }, 3,
              { if (more) ISSUE_HT(Ag, 0,     0, 1, W); },
              { if (more) { VM6; } else { VM0; } });
        PHASE({ LOAD_AF(1, 0); LOAD_BF(1, 0); }, 0,
              { if (more) ISSUE_HT(Bg, 65536, 0, 0, W); }, VM6);
        PHASE({ LOAD_BF(1, 1); }, 1,
              { if (more) ISSUE_HT(Ag, 0,     1, 0, X); }, VM6);
        PHASE({ LOAD_AF(1, 1); }, 2,
              { if (more) ISSUE_HT(Bg, 65536, 1, 1, X); }, VM6);
        PHASE({ LOAD_BF(1, 0); }, 3,
              { if (more) ISSUE_HT(Ag, 0,     1, 1, X); }, VM6);
    }

#undef PHASE
#undef VM0
#undef VM6
#undef LOAD_BF
#undef LOAD_AF
#undef ISSUE_HT

    // ---- epilogue. C/D layout (verified): col = lane&15, row = (lane>>4)*4 + reg.
    // Quad map: qd -> (mh, nh): 0=(0,0) 1=(0,1) 2=(1,1) 3=(1,0).
    const int col16 = lane & 15;
    const int rquad = (lane >> 4) * 4;
#pragma unroll
    for (int qd = 0; qd < 4; ++qd) {
        const int mh = qd >> 1;
        const int nh = (qd >> 1) ^ (qd & 1);
#pragma unroll
        for (int ni = 0; ni < 2; ++ni) {
            const int col = bn * BN + nh * 128 + wn * 32 + ni * 16 + col16;
            // match np ref arithmetic exactly: (0.05f * ws) / 0.1f, all f32
            float s = 0.05f * wscale[col];
            s = s / 0.1f;
            const float bz = (float)bias[col];
#pragma unroll
            for (int mi = 0; mi < 4; ++mi) {
                const int row0 = bm * BM + mh * 128 + wm * 64 + mi * 16 + rquad;
#pragma unroll
                for (int r = 0; r < 4; ++r) {
                    float v = ((float)acc[qd][mi][ni][r] + bz) * s;
                    v = rintf(v);                          // RTNE, matches np.round
                    v = fminf(fmaxf(v, -128.0f), 127.0f);
                    C[(size_t)(row0 + r) * N_DIM + col] = (int)v;
                }
            }
        }
    }
}

extern "C" void kernel_launch(void* const* d_in, const int* in_sizes, int n_in,
                              void* d_out, int out_size, void* d_ws, size_t ws_size,
                              hipStream_t stream) {
    const int*   x32    = (const int*)d_in[0];     // int8 values promoted to int32
    const int*   w32    = (const int*)d_in[1];
    const int*   bias   = (const int*)d_in[2];
    const float* wscale = (const float*)d_in[3];
    int*         out    = (int*)d_out;

    int8_t* xp = (int8_t*)d_ws;                         // 32 MiB packed x
    int8_t* wp = xp + (size_t)M_DIM * K_DIM;            // 16 MiB packed w

    {
        const int nxblocks = (int)((long)M_DIM * K_DIM / 4 / 1024);   // 8192
        const int nwblocks = (int)((long)N_DIM * K_DIM / 4 / 1024);   // 4096
        pack_i8_kernel<<<nxblocks + nwblocks, 256, 0, stream>>>(
            (const int4*)x32, (int*)xp, (const int4*)w32, (int*)wp, nxblocks);
    }

    dim3 grid(N_DIM / BN, M_DIM / BM);   // (16, 32)
    qgemm_i8_kernel<<<grid, 512, 0, stream>>>(xp, wp, bias, wscale, out);
}

// Round 7
// 389.227 us; speedup vs baseline: 1.7458x; 1.0012x over previous
//
#include <hip/hip_runtime.h>
#include <cstdint>
#include <cstddef>

// Problem constants
#define M_DIM 8192
#define N_DIM 4096
#define K_DIM 4096

#define BM 256
#define BN 256
// K-tile = 128 bytes of K per row; 2 K-tiles per iteration; 4096/256 = 16 iters.

using i32x4 = __attribute__((ext_vector_type(4))) int;

__device__ __forceinline__ void async_load16(const void* g, void* l) {
    __builtin_amdgcn_global_load_lds(
        (const __attribute__((address_space(1))) void*)g,
        (__attribute__((address_space(3))) void*)l,
        16, 0, 0);
}

// Pack int32 values (range [-128,127]) to int8, both buffers in one launch.
__global__ __launch_bounds__(256) void pack_i8_kernel(const int4* __restrict__ xsrc,
                                                      int* __restrict__ xdst,
                                                      const int4* __restrict__ wsrc,
                                                      int* __restrict__ wdst,
                                                      int nxblocks) {
    const bool isw = (int)blockIdx.x >= nxblocks;
    const int4* src = isw ? wsrc : xsrc;
    int*       dst  = isw ? wdst : xdst;
    const long bb   = isw ? ((long)blockIdx.x - nxblocks) : (long)blockIdx.x;
    const long base = bb * 1024 + threadIdx.x;
#pragma unroll
    for (int j = 0; j < 4; ++j) {
        const long i = base + 256 * j;
        const int4 v = src[i];
        dst[i] = (v.x & 0xff) | ((v.y & 0xff) << 8) | ((v.z & 0xff) << 16) | (v.w << 24);
    }
}

// 256x256-tile 8-phase i8 GEMM. Gray-code quadrant order (0,0)->(0,1)->(1,1)->(1,0);
// A-half fragments held across phases, BOTH B-halves held in registers
// (24 ds_read_b128 per wave per K-tile = the minimum for this wave-tiling).
// No forced lgkmcnt(0) drain before MFMA: the ds_reads are compiler-visible,
// so fine-grained lgkmcnt(N) per dependency lets early MFMAs overlap the
// tail of the fragment-load batch (r6's ~470 cyc/phase drain overhead).
// LDS map (128 KiB): A: buf*32768 + half*16384 + row*128; B: +65536.
// 16B chunks XOR-swizzled by (row&7) via pre-swizzled global source (rule 21).
__global__ __launch_bounds__(512, 2) void qgemm_i8_kernel(const int8_t* __restrict__ A,
                                                          const int8_t* __restrict__ B,
                                                          const int* __restrict__ bias,
                                                          const float* __restrict__ wscale,
                                                          int* __restrict__ C) {
    __shared__ int8_t LDS[131072];

    const int tid  = threadIdx.x;
    const int wave = tid >> 6;
    const int lane = tid & 63;
    const int wm = wave >> 2;   // 0..1
    const int wn = wave & 3;    // 0..3
    const int bm = blockIdx.y;
    const int bn = blockIdx.x;

    const int8_t* Ab = A + (size_t)bm * BM * K_DIM;
    const int8_t* Bb = B + (size_t)bn * BN * K_DIM;

    // Staging: per ISSUE_HT a wave covers 16 rows x 128B (2 x global_load_lds).
    // Lane l -> row +(l>>3), source chunk (l&7)^(l>>3) (pre-swizzled global).
    const int l8 = lane >> 3;
    const int l7 = lane & 7;
    const int8_t* Ag = Ab + (size_t)(wave * 16 + l8) * K_DIM + ((l7 ^ l8) * 16);
    const int8_t* Bg = Bb + (size_t)(wave * 16 + l8) * K_DIM + ((l7 ^ l8) * 16);
    const int sdst = wave * 2048;

    // Fragment ds_read bases. A row = mh*128 + wm*64 + mi*16 + (lane&15);
    // chunk = (kk*4 + (lane>>4)) ^ (row&7); row&7 == lane&7. kk=1 addr = kk=0 ^ 64.
    const int l15 = lane & 15;
    const int qh  = lane >> 4;
    const int a_off0 = wm * 8192 + l15 * 128 + ((qh ^ l7) * 16);
    const int a_off1 = a_off0 ^ 64;
    const int b_off0 = 65536 + wn * 4096 + l15 * 128 + ((qh ^ l7) * 16);
    const int b_off1 = b_off0 ^ 64;

    i32x4 acc[4][4][2] = {};   // [quadrant][mi][ni]
    i32x4 af[4][2];            // current A-half fragments (held across phases)
    i32x4 bf[2][2][2];         // BOTH B-half fragments [nh][ni][kk], held all K-tile

#define ISSUE_HT(GB, REG, BUF, HH, T) do { \
    async_load16((GB) + (size_t)((HH) * 128)     * K_DIM + (size_t)(T) * 128, \
                 &LDS[(REG) + (BUF) * 32768 + (HH) * 16384 + sdst]); \
    async_load16((GB) + (size_t)((HH) * 128 + 8) * K_DIM + (size_t)(T) * 128, \
                 &LDS[(REG) + (BUF) * 32768 + (HH) * 16384 + sdst + 1024]); \
} while (0)

#define LOAD_AF(BUF, MH) do { \
    _Pragma("unroll") \
    for (int mi = 0; mi < 4; ++mi) { \
        af[mi][0] = *(const i32x4*)&LDS[a_off0 + (BUF) * 32768 + (MH) * 16384 + mi * 2048]; \
        af[mi][1] = *(const i32x4*)&LDS[a_off1 + (BUF) * 32768 + (MH) * 16384 + mi * 2048]; \
    } \
} while (0)

#define LOAD_BF(BUF, NH) do { \
    _Pragma("unroll") \
    for (int ni = 0; ni < 2; ++ni) { \
        bf[NH][ni][0] = *(const i32x4*)&LDS[b_off0 + (BUF) * 32768 + (NH) * 16384 + ni * 2048]; \
        bf[NH][ni][1] = *(const i32x4*)&LDS[b_off1 + (BUF) * 32768 + (NH) * 16384 + ni * 2048]; \
    } \
} while (0)

#define VM6 asm volatile("s_waitcnt vmcnt(6)" ::: "memory")
#define VM0 asm volatile("s_waitcnt vmcnt(0)" ::: "memory")

#define PHASE(LOADS, QD, NHB, ISSUES, CHK) do { \
    LOADS; \
    ISSUES; \
    CHK; \
    __builtin_amdgcn_s_barrier(); \
    __builtin_amdgcn_s_setprio(1); \
    _Pragma("unroll") \
    for (int mi = 0; mi < 4; ++mi) { \
        _Pragma("unroll") \
        for (int ni = 0; ni < 2; ++ni) { \
            acc[QD][mi][ni] = __builtin_amdgcn_mfma_i32_16x16x64_i8(af[mi][0], bf[NHB][ni][0], acc[QD][mi][ni], 0, 0, 0); \
            acc[QD][mi][ni] = __builtin_amdgcn_mfma_i32_16x16x64_i8(af[mi][1], bf[NHB][ni][1], acc[QD][mi][ni], 0, 0, 0); \
        } \
    } \
    __builtin_amdgcn_s_setprio(0); \
    __builtin_amdgcn_s_barrier(); \
} while (0)

    // ---- prologue: tile0 fully + tile1 partial (A1h0, B1h1, A1h1).
    // B1h0(t1) is issued at P1 of iter 0. vmcnt(10) -> A0h0,B0h0 landed.
    ISSUE_HT(Ag, 0,     0, 0, 0);   // #1 A0h0
    ISSUE_HT(Bg, 65536, 0, 0, 0);   // #2 B0h0
    ISSUE_HT(Bg, 65536, 0, 1, 0);   // #3 B0h1
    ISSUE_HT(Ag, 0,     0, 1, 0);   // #4 A0h1
    ISSUE_HT(Ag, 0,     1, 0, 1);   // #5 A1h0
    ISSUE_HT(Bg, 65536, 1, 1, 1);   // #6 B1h1
    ISSUE_HT(Ag, 0,     1, 1, 1);   // #7 A1h1
    asm volatile("s_waitcnt vmcnt(10)" ::: "memory");
    __builtin_amdgcn_s_barrier();

    // ---- main loop. Iter i: tiles U=2i (buf0, P1-4), V=2i+1 (buf1, P5-8).
    // Quadrants: P1=(0,0) P2=(0,1) P3=(1,1) P4=(1,0); loads only the changed half;
    // P4/P8 reuse the B-half-0 registers from P1/P5 (no ds_read at all).
    // vmcnt(6) each phase => issues >=3 phases old have landed (FIFO-traced).
    // Region overwrites sit >=2 barriers after that region's last ds_read.
    for (int i = 0; i < 16; ++i) {
        const int V = 2 * i + 1;
        const int W = 2 * i + 2;   // -> buf0
        const int X = 2 * i + 3;   // -> buf1
        const bool more = (i < 15);

        PHASE({ LOAD_AF(0, 0); LOAD_BF(0, 0); }, 0, 0,
              { ISSUE_HT(Bg, 65536, 1, 0, V); }, VM6);
        PHASE({ LOAD_BF(0, 1); }, 1, 1,
              { if (more) ISSUE_HT(Ag, 0,     0, 0, W); }, VM6);
        PHASE({ LOAD_AF(0, 1); }, 2, 1,
              { if (more) ISSUE_HT(Bg, 65536, 0, 1, W); }, VM6);
        PHASE({}, 3, 0,
              { if (more) ISSUE_HT(Ag, 0,     0, 1, W); },
              { if (more) { VM6; } else { VM0; } });
        PHASE({ LOAD_AF(1, 0); LOAD_BF(1, 0); }, 0, 0,
              { if (more) ISSUE_HT(Bg, 65536, 0, 0, W); }, VM6);
        PHASE({ LOAD_BF(1, 1); }, 1, 1,
              { if (more) ISSUE_HT(Ag, 0,     1, 0, X); }, VM6);
        PHASE({ LOAD_AF(1, 1); }, 2, 1,
              { if (more) ISSUE_HT(Bg, 65536, 1, 1, X); }, VM6);
        PHASE({}, 3, 0,
              { if (more) ISSUE_HT(Ag, 0,     1, 1, X); }, VM6);
    }

#undef PHASE
#undef VM0
#undef VM6
#undef LOAD_BF
#undef LOAD_AF
#undef ISSUE_HT

    // ---- epilogue. C/D layout (verified): col = lane&15, row = (lane>>4)*4 + reg.
    // Quad map: qd -> (mh, nh): 0=(0,0) 1=(0,1) 2=(1,1) 3=(1,0).
    const int col16 = lane & 15;
    const int rquad = (lane >> 4) * 4;
#pragma unroll
    for (int qd = 0; qd < 4; ++qd) {
        const int mh = qd >> 1;
        const int nh = (qd >> 1) ^ (qd & 1);
#pragma unroll
        for (int ni = 0; ni < 2; ++ni) {
            const int col = bn * BN + nh * 128 + wn * 32 + ni * 16 + col16;
            // match np ref arithmetic exactly: (0.05f * ws) / 0.1f, all f32
            float s = 0.05f * wscale[col];
            s = s / 0.1f;
            const float bz = (float)bias[col];
#pragma unroll
            for (int mi = 0; mi < 4; ++mi) {
                const int row0 = bm * BM + mh * 128 + wm * 64 + mi * 16 + rquad;
#pragma unroll
                for (int r = 0; r < 4; ++r) {
                    float v = ((float)acc[qd][mi][ni][r] + bz) * s;
                    v = rintf(v);                          // RTNE, matches np.round
                    v = fminf(fmaxf(v, -128.0f), 127.0f);
                    C[(size_t)(row0 + r) * N_DIM + col] = (int)v;
                }
            }
        }
    }
}

extern "C" void kernel_launch(void* const* d_in, const int* in_sizes, int n_in,
                              void* d_out, int out_size, void* d_ws, size_t ws_size,
                              hipStream_t stream) {
    const int*   x32    = (const int*)d_in[0];     // int8 values promoted to int32
    const int*   w32    = (const int*)d_in[1];
    const int*   bias   = (const int*)d_in[2];
    const float* wscale = (const float*)d_in[3];
    int*         out    = (int*)d_out;

    int8_t* xp = (int8_t*)d_ws;                         // 32 MiB packed x
    int8_t* wp = xp + (size_t)M_DIM * K_DIM;            // 16 MiB packed w

    {
        const int nxblocks = (int)((long)M_DIM * K_DIM / 4 / 1024);   // 8192
        const int nwblocks = (int)((long)N_DIM * K_DIM / 4 / 1024);   // 4096
        pack_i8_kernel<<<nxblocks + nwblocks, 256, 0, stream>>>(
            (const int4*)x32, (int*)xp, (const int4*)w32, (int*)wp, nxblocks);
    }

    dim3 grid(N_DIM / BN, M_DIM / BM);   // (16, 32)
    qgemm_i8_kernel<<<grid, 512, 0, stream>>>(xp, wp, bias, wscale, out);
}